// Round 2
// baseline (45830.811 us; speedup 1.0000x reference)
//
#include <hip/hip_runtime.h>

typedef __bf16 bf16;
typedef __bf16 bf16x8 __attribute__((ext_vector_type(8)));
typedef float  f32x16 __attribute__((ext_vector_type(16)));
typedef unsigned short u16;
typedef u16 u16x4 __attribute__((ext_vector_type(4)));

#define MFMA(a,b,c) __builtin_amdgcn_mfma_f32_32x32x16_bf16((a),(b),(c),0,0,0)

#define BSZ  2048
#define H    256
#define NOUT 5
#define NG   32   // groups
#define GC   8    // CUs (blocks) per group
#define BM   64   // batch rows per group

// packed weight fragments (16B each): big mats frag id = (tile*16+ks)*64+lane
#define F_WHH1 0
#define F_WIH2 24576
#define F_WHH2 49152
#define F_WIH1 73728
#define F_LIN  75264
#define F_TOTAL 76288

__device__ bf16x8 g_pk[F_TOTAL];
__device__ unsigned g_flags[2][NG][GC];          // [phase][group][cu] step counters
__device__ u16 g_hx[2][2][NG][GC][32 * 64];      // [layer][parity][group][cu][jl*64+m] bf16 bits

__global__ void prepack_kernel(const float* __restrict__ wih1,
                               const float* __restrict__ whh1,
                               const float* __restrict__ wih2,
                               const float* __restrict__ whh2,
                               const float* __restrict__ lin_w) {
  int fid = blockIdx.x * 256 + threadIdx.x;
  if (fid >= F_TOTAL) return;
  bf16x8 v;
  if (fid < F_WIH1) {
    const float* W = (fid < F_WIH2) ? whh1 : (fid < F_WHH2) ? wih2 : whh2;
    int r    = fid % 24576;
    int tile = r >> 10;
    int ks   = (r >> 6) & 15;
    int lane = r & 63;
    int n = tile * 32 + (lane & 31);
    int k = ks * 16 + (lane >> 5) * 8;
    const float* p = W + n * 256 + k;
#pragma unroll
    for (int i = 0; i < 8; ++i) v[i] = (bf16)p[i];
  } else if (fid < F_LIN) {
    int r    = fid - F_WIH1;
    int tile = r >> 6;
    int lane = r & 63;
    int n  = tile * 32 + (lane & 31);
    int k0 = (lane >> 5) * 8;
#pragma unroll
    for (int i = 0; i < 8; ++i) {
      int kk = k0 + i;
      v[i] = (kk < 8) ? (bf16)wih1[n * 8 + kk] : (bf16)0.f;
    }
  } else {
    int r    = fid - F_LIN;
    int ks   = r >> 6;
    int lane = r & 63;
    int n = lane & 31;
    int k = ks * 16 + (lane >> 5) * 8;
#pragma unroll
    for (int i = 0; i < 8; ++i)
      v[i] = (n < NOUT) ? (bf16)lin_w[n * 256 + k + i] : (bf16)0.f;
  }
  g_pk[fid] = v;
}

__global__ void zero_flags_kernel() {
  ((unsigned*)g_flags)[threadIdx.x] = 0u;   // 2*32*8 = 512
}

__device__ __forceinline__ float sigmoidf_(float x) { return 1.f / (1.f + __expf(-x)); }
__device__ __forceinline__ float tanhf_(float x) {
  float e = __expf(-2.f * x);
  return (1.f - e) / (1.f + e);
}
__device__ __forceinline__ f32x16 z16() {
  f32x16 z;
#pragma unroll
  for (int i = 0; i < 16; ++i) z[i] = 0.f;
  return z;
}
__device__ __forceinline__ u16 bfb(float x) { bf16 b = (bf16)x; return *(u16*)&b; }

// swizzled bf16 A-tile element (row, unit u of 8 cols): 32-way-conflict-free ds_read_b128
__device__ __forceinline__ bf16x8 ldA(const u16* buf, int row, int u) {
  return *(const bf16x8*)&buf[(row << 8) + ((u ^ (row & 31)) << 3)];
}
__device__ __forceinline__ bf16x8 ldX(const u16* xsb, int row, int hv) {
  return *(const bf16x8*)&xsb[(row << 4) + (hv << 3)];
}

__device__ __forceinline__ void spin_wait(int ph, int grp, int l, unsigned tgt) {
  unsigned* f = &g_flags[ph][grp][0];
  for (;;) {
    bool ok = true;
    if (l < GC) ok = (__hip_atomic_load(&f[l], __ATOMIC_ACQUIRE, __HIP_MEMORY_SCOPE_AGENT) >= tgt);
    if (__all((int)ok)) break;
    __builtin_amdgcn_s_sleep(2);
  }
}

__device__ __forceinline__ void dump2(float* tile, int hv, int col,
                                      const f32x16& a0, const f32x16& a1) {
#pragma unroll
  for (int q = 0; q < 16; ++q) {
    int mm = (q & 3) + 8 * (q >> 2) + 4 * hv;
    tile[mm * 33 + col]        = a0[q];
    tile[(32 + mm) * 33 + col] = a1[q];
  }
}

#define CHAIN2(BUF, KOFF, KS0, NKS, A0, A1)                      \
  { _Pragma("unroll")                                            \
    for (int kk = 0; kk < (NKS); ++kk) {                         \
      int uu_ = 2 * ((KS0) + kk) + hv;                           \
      A0 = MFMA(ldA(BUF, col, uu_), wf[(KOFF) + kk], A0);        \
      A1 = MFMA(ldA(BUF, 32 + col, uu_), wf[(KOFF) + kk], A1);   \
    } }

// 8-CU groups, weights register-resident. CU g owns h-dims [32g,32g+32).
// Wave roles: 0/1/2 = L1 r/z/n (whh1+wih1, phase A); 3/4/5 = L2 gi r/z/n
// (wih2, phase B); 6/7 = L2 gh (whh2: w6=r + n-loK, w7=z + n-hiK, phase A).
// Gate recombination + activations in LDS f32 tiles; h masters f32 in LDS.
// Per-step 4KB h-slice exchange via g_hx + agent-scope flags (parity dbuf).
__global__ __launch_bounds__(512, 2) void gru_kernel(
    const int* __restrict__ plen_p,
    const float* __restrict__ rnn_in,
    const float* __restrict__ out0,
    const float* __restrict__ h01,
    const float* __restrict__ h02,
    const float* __restrict__ bih1, const float* __restrict__ bhh1,
    const float* __restrict__ bih2, const float* __restrict__ bhh2,
    const float* __restrict__ lin_b,
    float* __restrict__ out) {
  __shared__ u16 h1bf[64 * 256];      // full h1, bf16 bits, swizzled
  __shared__ u16 h2bf[64 * 256];
  __shared__ float preS[8][64 * 33];  // gate preact tiles (+1 pad)
  __shared__ float Mst1[64 * 33];     // own-slice f32 masters
  __shared__ float Mst2[64 * 33];
  __shared__ u16 xs[64 * 16];         // [out(5), u(3), zeros(8)]

  const int T   = plen_p[0];
  const int tid = threadIdx.x;
  const int wv  = tid >> 6;
  const int l   = tid & 63;
  const int col = l & 31;
  const int hv  = l >> 5;
  const int g   = blockIdx.x >> 5;   // CU rank in group (same-XCD grouping)
  const int grp = blockIdx.x & 31;
  const int b0  = grp * BM;

  // ---- register-resident weight fragments ----
  bf16x8 wf[24];
  if (wv < 3) {
    int tile = wv * 8 + g;
#pragma unroll
    for (int k = 0; k < 16; ++k) wf[k] = g_pk[F_WHH1 + (tile * 16 + k) * 64 + l];
    wf[16] = g_pk[F_WIH1 + tile * 64 + l];
  } else if (wv < 6) {
    int tile = (wv - 3) * 8 + g;
#pragma unroll
    for (int k = 0; k < 16; ++k) wf[k] = g_pk[F_WIH2 + (tile * 16 + k) * 64 + l];
  } else {
    int tile = (wv - 6) * 8 + g;
#pragma unroll
    for (int k = 0; k < 16; ++k) wf[k] = g_pk[F_WHH2 + (tile * 16 + k) * 64 + l];
    int tn = 16 + g, kb = (wv - 6) * 8;
#pragma unroll
    for (int k = 0; k < 8; ++k) wf[16 + k] = g_pk[F_WHH2 + (tn * 16 + kb + k) * 64 + l];
  }

  // ---- combine-phase biases (per thread: 4 own jl's) ----
  float br1v[4], bz1v[4], bi1v[4], bh1v[4];
  float br2v[4], bz2v[4], bi2v[4], bh2v[4];
#pragma unroll
  for (int i = 0; i < 4; ++i) {
    int J = 32 * g + 4 * wv + i;
    br1v[i] = bih1[J] + bhh1[J];
    bz1v[i] = bih1[H + J] + bhh1[H + J];
    bi1v[i] = bih1[2 * H + J];
    bh1v[i] = bhh1[2 * H + J];
    br2v[i] = bih2[J] + bhh2[J];
    bz2v[i] = bih2[H + J] + bhh2[H + J];
    bi2v[i] = bih2[2 * H + J];
    bh2v[i] = bhh2[2 * H + J];
  }
  float lb = 0.f;
  if ((wv == 2 || wv == 5) && col < NOUT) lb = lin_b[col];

  // ---- LDS init ----
  for (int r = tid; r < 64 * 32; r += 512) {
    int m = r >> 5, u8 = r & 31;
    const float* p1 = h01 + ((size_t)(b0 + m)) * H + u8 * 8;
    const float* p2 = h02 + ((size_t)(b0 + m)) * H + u8 * 8;
    bf16x8 v1, v2;
#pragma unroll
    for (int i = 0; i < 8; ++i) { v1[i] = (bf16)p1[i]; v2[i] = (bf16)p2[i]; }
    int off = (m << 8) + ((u8 ^ (m & 31)) << 3);
    *(bf16x8*)&h1bf[off] = v1;
    *(bf16x8*)&h2bf[off] = v2;
  }
  for (int r = tid; r < 64 * 32; r += 512) {
    int m = r >> 5, jl = r & 31;
    Mst1[m * 33 + jl] = h01[((size_t)(b0 + m)) * H + 32 * g + jl];
    Mst2[m * 33 + jl] = h02[((size_t)(b0 + m)) * H + 32 * g + jl];
  }
  {
    int m = tid >> 3, c = (tid & 7) + 8;
    xs[m * 16 + c] = 0;
    if (tid < 320) { int mm = tid / 5, cc = tid % 5; xs[mm * 16 + cc] = bfb(out0[(size_t)(b0 + mm) * NOUT + cc]); }
    if (tid < 192) { int mm = tid / 3, cc = tid % 3; xs[mm * 16 + 5 + cc] = bfb(rnn_in[((size_t)(b0 + mm)) * 4 + cc]); }
  }
  __syncthreads();

  for (int t = 0; t < T; ++t) {
    const int par = t & 1;
    float ux = 0.f, uy = 0.f, uz = 0.f;

    // ============ phase A: L1 chains + whh2 (gh2) chains ============
    if (wv < 2) {
      f32x16 a0 = z16(), a1 = z16();
      CHAIN2(h1bf, 0, 0, 16, a0, a1);
      a0 = MFMA(ldX(xs, col, hv), wf[16], a0);
      a1 = MFMA(ldX(xs, 32 + col, hv), wf[16], a1);
      dump2(preS[wv], hv, col, a0, a1);                 // hr1 / hz1 (i+h merged, raw)
    } else if (wv == 2) {
      f32x16 a0 = z16(), a1 = z16();
      a0 = MFMA(ldX(xs, col, hv), wf[16], a0);
      a1 = MFMA(ldX(xs, 32 + col, hv), wf[16], a1);
      dump2(preS[3], hv, col, a0, a1);                  // i_n1 (raw)
      f32x16 c0 = z16(), c1 = z16();
      CHAIN2(h1bf, 0, 0, 16, c0, c1);
      dump2(preS[2], hv, col, c0, c1);                  // h_n1 (raw)
    } else if (wv == 3) {
      if (t + 1 < T) {
        const float4 uu = *(const float4*)&rnn_in[((size_t)(t + 1) * BSZ + b0 + l) * 4];
        ux = uu.x; uy = uu.y; uz = uu.z;
      }
    } else if (wv >= 6) {
      f32x16 a0 = z16(), a1 = z16();
      CHAIN2(h2bf, 0, 0, 16, a0, a1);
      dump2(preS[4 + (wv & 1)], hv, col, a0, a1);       // gh_r2 / gh_z2
      f32x16 c0 = z16(), c1 = z16();
      if (wv == 6) { CHAIN2(h2bf, 16, 0, 8, c0, c1); }
      else         { CHAIN2(h2bf, 16, 8, 8, c0, c1); }
      dump2(preS[6 + (wv & 1)], hv, col, c0, c1);       // gh_n2 halves
    }
    __syncthreads();  // bar1

    // ============ combine h1 (all waves) ============
    {
      u16* slab = &g_hx[0][par][grp][g][0];
#pragma unroll
      for (int i = 0; i < 4; ++i) {
        int jl = (wv << 2) + i;
        float pr  = preS[0][l * 33 + jl];
        float pz  = preS[1][l * 33 + jl];
        float hn  = preS[2][l * 33 + jl];
        float xin = preS[3][l * 33 + jl];
        float hp  = Mst1[l * 33 + jl];
        float r = sigmoidf_(pr + br1v[i]);
        float z = sigmoidf_(pz + bz1v[i]);
        float n = tanhf_(xin + bi1v[i] + r * (hn + bh1v[i]));
        float h = (1.f - z) * n + z * hp;
        Mst1[l * 33 + jl] = h;
        u16 hb = bfb(h);
        slab[jl * 64 + l] = hb;
        int J = (g << 5) + jl;
        h1bf[(l << 8) + (((J >> 3) ^ (l & 31)) << 3) + (J & 7)] = hb;
      }
    }
    __threadfence();
    __syncthreads();  // bar2
    if (tid == 0) __hip_atomic_fetch_add(&g_flags[0][grp][g], 1u, __ATOMIC_RELEASE, __HIP_MEMORY_SCOPE_AGENT);
    spin_wait(0, grp, l, (unsigned)(t + 1));
    {
      int jl = tid >> 4, m4 = (tid & 15) << 2;
      const u16* base = &g_hx[0][par][grp][0][0];
      for (int gi = 0; gi < GC; ++gi) {
        if (gi == g) continue;
        u16x4 v = *(const u16x4*)(base + gi * 2048 + jl * 64 + m4);
        int J = (gi << 5) + jl;
        int ju = J >> 3, jr = J & 7;
#pragma unroll
        for (int k = 0; k < 4; ++k) {
          int m = m4 + k;
          h1bf[(m << 8) + ((ju ^ (m & 31)) << 3) + jr] = v[k];
        }
      }
    }
    __syncthreads();  // bar3

    // ============ phase B: wih2 (gi2) chains from fresh h1 ============
    if (wv >= 3 && wv < 6) {
      f32x16 a0 = z16(), a1 = z16();
      CHAIN2(h1bf, 0, 0, 16, a0, a1);
      dump2(preS[wv == 3 ? 0 : (wv == 4 ? 1 : 3)], hv, col, a0, a1);
    }
    __syncthreads();  // bar4

    // ============ combine h2 (all waves) ============
    {
      u16* slab = &g_hx[1][par][grp][g][0];
#pragma unroll
      for (int i = 0; i < 4; ++i) {
        int jl = (wv << 2) + i;
        float gir = preS[0][l * 33 + jl], ghr = preS[4][l * 33 + jl];
        float giz = preS[1][l * 33 + jl], ghz = preS[5][l * 33 + jl];
        float gin = preS[3][l * 33 + jl];
        float ghn = preS[6][l * 33 + jl] + preS[7][l * 33 + jl];
        float hp  = Mst2[l * 33 + jl];
        float r = sigmoidf_(gir + ghr + br2v[i]);
        float z = sigmoidf_(giz + ghz + bz2v[i]);
        float n = tanhf_(gin + bi2v[i] + r * (ghn + bh2v[i]));
        float h = (1.f - z) * n + z * hp;
        Mst2[l * 33 + jl] = h;
        u16 hb = bfb(h);
        slab[jl * 64 + l] = hb;
        int J = (g << 5) + jl;
        h2bf[(l << 8) + (((J >> 3) ^ (l & 31)) << 3) + (J & 7)] = hb;
      }
    }
    __threadfence();
    __syncthreads();  // bar5
    if (tid == 0) __hip_atomic_fetch_add(&g_flags[1][grp][g], 1u, __ATOMIC_RELEASE, __HIP_MEMORY_SCOPE_AGENT);
    spin_wait(1, grp, l, (unsigned)(t + 1));
    {
      int jl = tid >> 4, m4 = (tid & 15) << 2;
      const u16* base = &g_hx[1][par][grp][0][0];
      for (int gi = 0; gi < GC; ++gi) {
        if (gi == g) continue;
        u16x4 v = *(const u16x4*)(base + gi * 2048 + jl * 64 + m4);
        int J = (gi << 5) + jl;
        int ju = J >> 3, jr = J & 7;
#pragma unroll
        for (int k = 0; k < 4; ++k) {
          int m = m4 + k;
          h2bf[(m << 8) + ((ju ^ (m & 31)) << 3) + jr] = v[k];
        }
      }
    }
    __syncthreads();  // bar6

    // ============ head: out = h2 @ lin^T (redundant per CU) + next x ============
    if (wv == 2 || wv == 5) {
      int mt = (wv == 2) ? 0 : 1;
      f32x16 a0 = z16();
#pragma unroll
      for (int ks = 0; ks < 16; ++ks)
        a0 = MFMA(ldA(h2bf, mt * 32 + col, 2 * ks + hv), g_pk[F_LIN + ks * 64 + l], a0);
      if (col < NOUT) {
#pragma unroll
        for (int q = 0; q < 16; ++q) {
          int m = mt * 32 + (q & 3) + 8 * (q >> 2) + 4 * hv;
          float v = a0[q] + lb;
          if (g == 0) out[((size_t)(b0 + m) * T + t) * NOUT + col] = v;
          xs[(m << 4) + col] = bfb(v);
        }
      }
    } else if (wv == 3) {
      if (t + 1 < T) {
        xs[(l << 4) + 5] = bfb(ux);
        xs[(l << 4) + 6] = bfb(uy);
        xs[(l << 4) + 7] = bfb(uz);
      }
    }
    __syncthreads();  // bar7
  }
}

extern "C" void kernel_launch(void* const* d_in, const int* in_sizes, int n_in,
                              void* d_out, int out_size, void* d_ws, size_t ws_size,
                              hipStream_t stream) {
  (void)in_sizes; (void)n_in; (void)out_size; (void)d_ws; (void)ws_size;
  const int*   plen  = (const int*)d_in[0];
  const float* rnn   = (const float*)d_in[1];
  const float* out0  = (const float*)d_in[2];
  const float* h01   = (const float*)d_in[3];
  const float* h02   = (const float*)d_in[4];
  const float* wih1  = (const float*)d_in[5];
  const float* whh1  = (const float*)d_in[6];
  const float* bih1  = (const float*)d_in[7];
  const float* bhh1  = (const float*)d_in[8];
  const float* wih2  = (const float*)d_in[9];
  const float* whh2  = (const float*)d_in[10];
  const float* bih2  = (const float*)d_in[11];
  const float* bhh2  = (const float*)d_in[12];
  const float* lin_w = (const float*)d_in[13];
  const float* lin_b = (const float*)d_in[14];

  zero_flags_kernel<<<1, 512, 0, stream>>>();
  prepack_kernel<<<(F_TOTAL + 255) / 256, 256, 0, stream>>>(wih1, whh1, wih2, whh2, lin_w);
  gru_kernel<<<NG * GC, 512, 0, stream>>>(plen, rnn, out0, h01, h02,
                                          bih1, bhh1, bih2, bhh2, lin_b,
                                          (float*)d_out);
}

// Round 3
// 5195.248 us; speedup vs baseline: 8.8217x; 8.8217x over previous
//
#include <hip/hip_runtime.h>

typedef __bf16 bf16;
typedef __bf16 bf16x8 __attribute__((ext_vector_type(8)));
typedef float  f32x16 __attribute__((ext_vector_type(16)));
typedef unsigned short u16;
typedef u16 u16x4 __attribute__((ext_vector_type(4)));
typedef unsigned long long u64;

#define MFMA(a,b,c) __builtin_amdgcn_mfma_f32_32x32x16_bf16((a),(b),(c),0,0,0)

#define BSZ  2048
#define H    256
#define NOUT 5
#define NG   32   // groups
#define GC   8    // CUs (blocks) per group
#define BM   64   // batch rows per group

// packed weight fragments (16B each): big mats frag id = (tile*16+ks)*64+lane
#define F_WHH1 0
#define F_WIH2 24576
#define F_WHH2 49152
#define F_WIH1 73728
#define F_LIN  75264
#define F_TOTAL 76288

__device__ bf16x8 g_pk[F_TOTAL];
__device__ unsigned g_flags[2][NG][GC];        // [phase][group][cu] step counters
__device__ u64 g_hx[2][2][NG][GC][512];        // [layer][parity][grp][cu][m*8+quad] 4xbf16

__global__ void prepack_kernel(const float* __restrict__ wih1,
                               const float* __restrict__ whh1,
                               const float* __restrict__ wih2,
                               const float* __restrict__ whh2,
                               const float* __restrict__ lin_w) {
  int fid = blockIdx.x * 256 + threadIdx.x;
  if (fid >= F_TOTAL) return;
  bf16x8 v;
  if (fid < F_WIH1) {
    const float* W = (fid < F_WIH2) ? whh1 : (fid < F_WHH2) ? wih2 : whh2;
    int r    = fid % 24576;
    int tile = r >> 10;
    int ks   = (r >> 6) & 15;
    int lane = r & 63;
    int n = tile * 32 + (lane & 31);
    int k = ks * 16 + (lane >> 5) * 8;
    const float* p = W + n * 256 + k;
#pragma unroll
    for (int i = 0; i < 8; ++i) v[i] = (bf16)p[i];
  } else if (fid < F_LIN) {
    int r    = fid - F_WIH1;
    int tile = r >> 6;
    int lane = r & 63;
    int n  = tile * 32 + (lane & 31);
    int k0 = (lane >> 5) * 8;
#pragma unroll
    for (int i = 0; i < 8; ++i) {
      int kk = k0 + i;
      v[i] = (kk < 8) ? (bf16)wih1[n * 8 + kk] : (bf16)0.f;
    }
  } else {
    int r    = fid - F_LIN;
    int ks   = r >> 6;
    int lane = r & 63;
    int n = lane & 31;
    int k = ks * 16 + (lane >> 5) * 8;
#pragma unroll
    for (int i = 0; i < 8; ++i)
      v[i] = (n < NOUT) ? (bf16)lin_w[n * 256 + k + i] : (bf16)0.f;
  }
  g_pk[fid] = v;
}

__global__ void zero_flags_kernel() {
  ((unsigned*)g_flags)[threadIdx.x] = 0u;   // 2*32*8 = 512
}

__device__ __forceinline__ float sigmoidf_(float x) { return 1.f / (1.f + __expf(-x)); }
__device__ __forceinline__ float tanhf_(float x) {
  float e = __expf(-2.f * x);
  return (1.f - e) / (1.f + e);
}
__device__ __forceinline__ f32x16 z16() {
  f32x16 z;
#pragma unroll
  for (int i = 0; i < 16; ++i) z[i] = 0.f;
  return z;
}
__device__ __forceinline__ u16 bfb(float x) { bf16 b = (bf16)x; return *(u16*)&b; }

// swizzled bf16 A-tile element (row, unit u of 8 cols): conflict-free ds_read_b128
__device__ __forceinline__ bf16x8 ldA(const u16* buf, int row, int u) {
  return *(const bf16x8*)&buf[(row << 8) + ((u ^ (row & 31)) << 3)];
}
__device__ __forceinline__ bf16x8 ldX(const u16* xsb, int row, int hv) {
  return *(const bf16x8*)&xsb[(row << 4) + (hv << 3)];
}

// relaxed agent atomics: sc1 cache-bypass to IF, NO invalidate/writeback
__device__ __forceinline__ void spin_wait(int ph, int grp, int l, unsigned tgt) {
  const unsigned* f = &g_flags[ph][grp][0];
  for (;;) {
    bool ok = true;
    if (l < GC) ok = (__hip_atomic_load(&f[l], __ATOMIC_RELAXED, __HIP_MEMORY_SCOPE_AGENT) >= tgt);
    if (__all((int)ok)) break;
    __builtin_amdgcn_s_sleep(1);
  }
}

__device__ __forceinline__ void dump2(float* tile, int hv, int col,
                                      const f32x16& a0, const f32x16& a1) {
#pragma unroll
  for (int q = 0; q < 16; ++q) {
    int mm = (q & 3) + 8 * (q >> 2) + 4 * hv;
    tile[mm * 33 + col]        = a0[q];
    tile[(32 + mm) * 33 + col] = a1[q];
  }
}

#define CHAIN2(BUF, KOFF, KS0, NKS, A0, A1)                      \
  { _Pragma("unroll")                                            \
    for (int kk = 0; kk < (NKS); ++kk) {                         \
      int uu_ = 2 * ((KS0) + kk) + hv;                           \
      A0 = MFMA(ldA(BUF, col, uu_), wf[(KOFF) + kk], A0);        \
      A1 = MFMA(ldA(BUF, 32 + col, uu_), wf[(KOFF) + kk], A1);   \
    } }

// 8-CU groups, weights register-resident. CU g owns h-dims [32g,32g+32).
// Waves 0/1/2 = L1 r/z/n (whh1+wih1, phase A); 3/4/5 = L2 gi r/z/n (wih2,
// phase B); 6/7 = L2 gh (whh2) — run during the h1-exchange spin window.
// Exchange: u64 relaxed agent atomics (IF-coherent, fence-free) + parity dbuf.
__global__ __launch_bounds__(512, 2) void gru_kernel(
    const int* __restrict__ plen_p,
    const float* __restrict__ rnn_in,
    const float* __restrict__ out0,
    const float* __restrict__ h01,
    const float* __restrict__ h02,
    const float* __restrict__ bih1, const float* __restrict__ bhh1,
    const float* __restrict__ bih2, const float* __restrict__ bhh2,
    const float* __restrict__ lin_b,
    float* __restrict__ out) {
  __shared__ u16 h1bf[64 * 256];      // full h1, bf16 bits, swizzled
  __shared__ u16 h2bf[64 * 256];
  __shared__ float preS[8][64 * 33];  // gate preact tiles (+1 pad)
  __shared__ float Mst1[64 * 33];     // own-slice f32 masters
  __shared__ float Mst2[64 * 33];
  __shared__ u16 xs[64 * 16];         // [out(5), u(3), zeros(8)]

  const int T   = plen_p[0];
  const int tid = threadIdx.x;
  const int wv  = tid >> 6;
  const int l   = tid & 63;
  const int col = l & 31;
  const int hv  = l >> 5;
  const int g   = blockIdx.x >> 5;   // CU rank in group (same blockIdx%8 cohort)
  const int grp = blockIdx.x & 31;
  const int b0  = grp * BM;

  // ---- register-resident weight fragments ----
  bf16x8 wf[24];
  if (wv < 3) {
    int tile = wv * 8 + g;
#pragma unroll
    for (int k = 0; k < 16; ++k) wf[k] = g_pk[F_WHH1 + (tile * 16 + k) * 64 + l];
    wf[16] = g_pk[F_WIH1 + tile * 64 + l];
  } else if (wv < 6) {
    int tile = (wv - 3) * 8 + g;
#pragma unroll
    for (int k = 0; k < 16; ++k) wf[k] = g_pk[F_WIH2 + (tile * 16 + k) * 64 + l];
  } else {
    int tile = (wv - 6) * 8 + g;
#pragma unroll
    for (int k = 0; k < 16; ++k) wf[k] = g_pk[F_WHH2 + (tile * 16 + k) * 64 + l];
    int tn = 16 + g, kb = (wv - 6) * 8;
#pragma unroll
    for (int k = 0; k < 8; ++k) wf[16 + k] = g_pk[F_WHH2 + (tn * 16 + kb + k) * 64 + l];
  }

  // ---- combine-phase biases (per thread: 4 own jl's) ----
  float br1v[4], bz1v[4], bi1v[4], bh1v[4];
  float br2v[4], bz2v[4], bi2v[4], bh2v[4];
#pragma unroll
  for (int i = 0; i < 4; ++i) {
    int J = 32 * g + 4 * wv + i;
    br1v[i] = bih1[J] + bhh1[J];
    bz1v[i] = bih1[H + J] + bhh1[H + J];
    bi1v[i] = bih1[2 * H + J];
    bh1v[i] = bhh1[2 * H + J];
    br2v[i] = bih2[J] + bhh2[J];
    bz2v[i] = bih2[H + J] + bhh2[H + J];
    bi2v[i] = bih2[2 * H + J];
    bh2v[i] = bhh2[2 * H + J];
  }
  float lb = 0.f;
  if ((wv == 2 || wv == 5) && col < NOUT) lb = lin_b[col];

  // ---- LDS init ----
  for (int r = tid; r < 64 * 32; r += 512) {
    int m = r >> 5, u8 = r & 31;
    const float* p1 = h01 + ((size_t)(b0 + m)) * H + u8 * 8;
    const float* p2 = h02 + ((size_t)(b0 + m)) * H + u8 * 8;
    bf16x8 v1, v2;
#pragma unroll
    for (int i = 0; i < 8; ++i) { v1[i] = (bf16)p1[i]; v2[i] = (bf16)p2[i]; }
    int off = (m << 8) + ((u8 ^ (m & 31)) << 3);
    *(bf16x8*)&h1bf[off] = v1;
    *(bf16x8*)&h2bf[off] = v2;
  }
  for (int r = tid; r < 64 * 32; r += 512) {
    int m = r >> 5, jl = r & 31;
    Mst1[m * 33 + jl] = h01[((size_t)(b0 + m)) * H + 32 * g + jl];
    Mst2[m * 33 + jl] = h02[((size_t)(b0 + m)) * H + 32 * g + jl];
  }
  {
    int m = tid >> 3, c = (tid & 7) + 8;
    xs[m * 16 + c] = 0;
    if (tid < 320) { int mm = tid / 5, cc = tid % 5; xs[mm * 16 + cc] = bfb(out0[(size_t)(b0 + mm) * NOUT + cc]); }
    if (tid < 192) { int mm = tid / 3, cc = tid % 3; xs[mm * 16 + 5 + cc] = bfb(rnn_in[((size_t)(b0 + mm)) * 4 + cc]); }
  }
  __syncthreads();

  for (int t = 0; t < T; ++t) {
    const int par = t & 1;
    float ux = 0.f, uy = 0.f, uz = 0.f;

    // ============ phase A: L1 chains (wv0-2); u prefetch (wv3) ============
    if (wv < 2) {
      f32x16 a0 = z16(), a1 = z16();
      CHAIN2(h1bf, 0, 0, 16, a0, a1);
      a0 = MFMA(ldX(xs, col, hv), wf[16], a0);
      a1 = MFMA(ldX(xs, 32 + col, hv), wf[16], a1);
      dump2(preS[wv], hv, col, a0, a1);                 // hr1 / hz1 (merged raw)
    } else if (wv == 2) {
      f32x16 a0 = z16(), a1 = z16();
      a0 = MFMA(ldX(xs, col, hv), wf[16], a0);
      a1 = MFMA(ldX(xs, 32 + col, hv), wf[16], a1);
      dump2(preS[3], hv, col, a0, a1);                  // i_n1 (raw)
      f32x16 c0 = z16(), c1 = z16();
      CHAIN2(h1bf, 0, 0, 16, c0, c1);
      dump2(preS[2], hv, col, c0, c1);                  // h_n1 (raw)
    } else if (wv == 3) {
      if (t + 1 < T) {
        const float4 uu = *(const float4*)&rnn_in[((size_t)(t + 1) * BSZ + b0 + l) * 4];
        ux = uu.x; uy = uu.y; uz = uu.z;
      }
    }
    __syncthreads();  // bar1

    // ============ combine h1 (all waves) ============
    {
      u16x4 v4;
#pragma unroll
      for (int i = 0; i < 4; ++i) {
        int jl = (wv << 2) + i;
        float pr  = preS[0][l * 33 + jl];
        float pz  = preS[1][l * 33 + jl];
        float hn  = preS[2][l * 33 + jl];
        float xin = preS[3][l * 33 + jl];
        float hp  = Mst1[l * 33 + jl];
        float r = sigmoidf_(pr + br1v[i]);
        float z = sigmoidf_(pz + bz1v[i]);
        float n = tanhf_(xin + bi1v[i] + r * (hn + bh1v[i]));
        float h = (1.f - z) * n + z * hp;
        Mst1[l * 33 + jl] = h;
        v4[i] = bfb(h);
      }
      int J0 = (g << 5) + (wv << 2);
      *(u16x4*)&h1bf[(l << 8) + (((J0 >> 3) ^ (l & 31)) << 3) + (J0 & 7)] = v4;
      __hip_atomic_store(&g_hx[0][par][grp][g][(l << 3) + wv],
                         __builtin_bit_cast(u64, v4),
                         __ATOMIC_RELAXED, __HIP_MEMORY_SCOPE_AGENT);
    }
    asm volatile("s_waitcnt vmcnt(0)" ::: "memory");
    __syncthreads();  // bar2  (all payload stores IF-visible)
    if (tid == 0)
      __hip_atomic_store(&g_flags[0][grp][g], (unsigned)(t + 1),
                         __ATOMIC_RELAXED, __HIP_MEMORY_SCOPE_AGENT);

    // ============ whh2 chains (wv6-7) — hidden under h1 exchange ============
    if (wv >= 6) {
      f32x16 a0 = z16(), a1 = z16();
      CHAIN2(h2bf, 0, 0, 16, a0, a1);
      dump2(preS[4 + (wv & 1)], hv, col, a0, a1);       // gh_r2 / gh_z2
      f32x16 c0 = z16(), c1 = z16();
      if (wv == 6) { CHAIN2(h2bf, 16, 0, 8, c0, c1); }
      else         { CHAIN2(h2bf, 16, 8, 8, c0, c1); }
      dump2(preS[6 + (wv & 1)], hv, col, c0, c1);       // gh_n2 halves
    }

    // ============ h1 exchange: spin + gather ============
    spin_wait(0, grp, l, (unsigned)(t + 1));
    {
      const int m = tid >> 3, jlq = tid & 7;
      u64 vals[GC];
#pragma unroll
      for (int gi = 0; gi < GC; ++gi)
        vals[gi] = __hip_atomic_load(&g_hx[0][par][grp][gi][tid],
                                     __ATOMIC_RELAXED, __HIP_MEMORY_SCOPE_AGENT);
#pragma unroll
      for (int gi = 0; gi < GC; ++gi) {
        int J0 = (gi << 5) + (jlq << 2);
        *(u16x4*)&h1bf[(m << 8) + (((J0 >> 3) ^ (m & 31)) << 3) + (J0 & 7)] =
            __builtin_bit_cast(u16x4, vals[gi]);
      }
    }
    __syncthreads();  // bar3

    // ============ phase B: wih2 (gi2) chains from fresh h1 ============
    if (wv >= 3 && wv < 6) {
      f32x16 a0 = z16(), a1 = z16();
      CHAIN2(h1bf, 0, 0, 16, a0, a1);
      dump2(preS[wv == 3 ? 0 : (wv == 4 ? 1 : 3)], hv, col, a0, a1);
    }
    __syncthreads();  // bar4

    // ============ combine h2 (all waves) ============
    {
      u16x4 v4;
#pragma unroll
      for (int i = 0; i < 4; ++i) {
        int jl = (wv << 2) + i;
        float gir = preS[0][l * 33 + jl], ghr = preS[4][l * 33 + jl];
        float giz = preS[1][l * 33 + jl], ghz = preS[5][l * 33 + jl];
        float gin = preS[3][l * 33 + jl];
        float ghn = preS[6][l * 33 + jl] + preS[7][l * 33 + jl];
        float hp  = Mst2[l * 33 + jl];
        float r = sigmoidf_(gir + ghr + br2v[i]);
        float z = sigmoidf_(giz + ghz + bz2v[i]);
        float n = tanhf_(gin + bi2v[i] + r * (ghn + bh2v[i]));
        float h = (1.f - z) * n + z * hp;
        Mst2[l * 33 + jl] = h;
        v4[i] = bfb(h);
      }
      int J0 = (g << 5) + (wv << 2);
      *(u16x4*)&h2bf[(l << 8) + (((J0 >> 3) ^ (l & 31)) << 3) + (J0 & 7)] = v4;
      __hip_atomic_store(&g_hx[1][par][grp][g][(l << 3) + wv],
                         __builtin_bit_cast(u64, v4),
                         __ATOMIC_RELAXED, __HIP_MEMORY_SCOPE_AGENT);
    }
    asm volatile("s_waitcnt vmcnt(0)" ::: "memory");
    __syncthreads();  // bar5
    if (tid == 0)
      __hip_atomic_store(&g_flags[1][grp][g], (unsigned)(t + 1),
                         __ATOMIC_RELAXED, __HIP_MEMORY_SCOPE_AGENT);

    // ============ h2 exchange: spin + gather ============
    spin_wait(1, grp, l, (unsigned)(t + 1));
    {
      const int m = tid >> 3, jlq = tid & 7;
      u64 vals[GC];
#pragma unroll
      for (int gi = 0; gi < GC; ++gi)
        vals[gi] = __hip_atomic_load(&g_hx[1][par][grp][gi][tid],
                                     __ATOMIC_RELAXED, __HIP_MEMORY_SCOPE_AGENT);
#pragma unroll
      for (int gi = 0; gi < GC; ++gi) {
        int J0 = (gi << 5) + (jlq << 2);
        *(u16x4*)&h2bf[(m << 8) + (((J0 >> 3) ^ (m & 31)) << 3) + (J0 & 7)] =
            __builtin_bit_cast(u16x4, vals[gi]);
      }
    }
    __syncthreads();  // bar6

    // ============ head: out = h2 @ lin^T (redundant per CU) + next x ============
    if (wv == 2 || wv == 5) {
      int mt = (wv == 2) ? 0 : 1;
      f32x16 a0 = z16();
#pragma unroll
      for (int ks = 0; ks < 16; ++ks)
        a0 = MFMA(ldA(h2bf, mt * 32 + col, 2 * ks + hv), g_pk[F_LIN + ks * 64 + l], a0);
      if (col < NOUT) {
#pragma unroll
        for (int q = 0; q < 16; ++q) {
          int m = mt * 32 + (q & 3) + 8 * (q >> 2) + 4 * hv;
          float v = a0[q] + lb;
          if (g == 0) out[((size_t)(b0 + m) * T + t) * NOUT + col] = v;
          xs[(m << 4) + col] = bfb(v);
        }
      }
    } else if (wv == 3) {
      if (t + 1 < T) {
        xs[(l << 4) + 5] = bfb(ux);
        xs[(l << 4) + 6] = bfb(uy);
        xs[(l << 4) + 7] = bfb(uz);
      }
    }
    __syncthreads();  // bar7
  }
}

extern "C" void kernel_launch(void* const* d_in, const int* in_sizes, int n_in,
                              void* d_out, int out_size, void* d_ws, size_t ws_size,
                              hipStream_t stream) {
  (void)in_sizes; (void)n_in; (void)out_size; (void)d_ws; (void)ws_size;
  const int*   plen  = (const int*)d_in[0];
  const float* rnn   = (const float*)d_in[1];
  const float* out0  = (const float*)d_in[2];
  const float* h01   = (const float*)d_in[3];
  const float* h02   = (const float*)d_in[4];
  const float* wih1  = (const float*)d_in[5];
  const float* whh1  = (const float*)d_in[6];
  const float* bih1  = (const float*)d_in[7];
  const float* bhh1  = (const float*)d_in[8];
  const float* wih2  = (const float*)d_in[9];
  const float* whh2  = (const float*)d_in[10];
  const float* bih2  = (const float*)d_in[11];
  const float* bhh2  = (const float*)d_in[12];
  const float* lin_w = (const float*)d_in[13];
  const float* lin_b = (const float*)d_in[14];

  zero_flags_kernel<<<1, 512, 0, stream>>>();
  prepack_kernel<<<(F_TOTAL + 255) / 256, 256, 0, stream>>>(wih1, whh1, wih2, whh2, lin_w);
  gru_kernel<<<NG * GC, 512, 0, stream>>>(plen, rnn, out0, h01, h02,
                                          bih1, bhh1, bih2, bhh2, lin_b,
                                          (float*)d_out);
}

// Round 5
// 4939.932 us; speedup vs baseline: 9.2776x; 1.0517x over previous
//
#include <hip/hip_runtime.h>

typedef __bf16 bf16;
typedef __bf16 bf16x8 __attribute__((ext_vector_type(8)));
typedef float  f32x16 __attribute__((ext_vector_type(16)));
typedef unsigned short u16;
typedef u16 u16x4 __attribute__((ext_vector_type(4)));
typedef unsigned long long u64;

#define MFMA(a,b,c) __builtin_amdgcn_mfma_f32_32x32x16_bf16((a),(b),(c),0,0,0)

#define BSZ  2048
#define H    256
#define NOUT 5
#define NG   32   // groups
#define GC   8    // CUs (blocks) per group
#define BM   64   // batch rows per group

// packed weight fragments (16B each): big mats frag id = (tile*16+ks)*64+lane
#define F_WHH1 0
#define F_WIH2 24576
#define F_WHH2 49152
#define F_WIH1 73728
#define F_LIN  75264
#define F_TOTAL 76288

__device__ bf16x8 g_pk[F_TOTAL];
// flags padded to 256B per (phase,group): no IF-line sharing across groups
__device__ __attribute__((aligned(256))) unsigned g_flags[2][NG][64];
// payload slabs: [layer][parity][grp][cu][quad*64+row] (4KB/slab, coalesced)
__device__ __attribute__((aligned(4096))) u64 g_hx[2][2][NG][GC][512];

__global__ void prepack_kernel(const float* __restrict__ wih1,
                               const float* __restrict__ whh1,
                               const float* __restrict__ wih2,
                               const float* __restrict__ whh2,
                               const float* __restrict__ lin_w) {
  int fid = blockIdx.x * 256 + threadIdx.x;
  if (fid >= F_TOTAL) return;
  bf16x8 v;
  if (fid < F_WIH1) {
    const float* W = (fid < F_WIH2) ? whh1 : (fid < F_WHH2) ? wih2 : whh2;
    int r    = fid % 24576;
    int tile = r >> 10;
    int ks   = (r >> 6) & 15;
    int lane = r & 63;
    int n = tile * 32 + (lane & 31);
    int k = ks * 16 + (lane >> 5) * 8;
    const float* p = W + n * 256 + k;
#pragma unroll
    for (int i = 0; i < 8; ++i) v[i] = (bf16)p[i];
  } else if (fid < F_LIN) {
    int r    = fid - F_WIH1;
    int tile = r >> 6;
    int lane = r & 63;
    int n  = tile * 32 + (lane & 31);
    int k0 = (lane >> 5) * 8;
#pragma unroll
    for (int i = 0; i < 8; ++i) {
      int kk = k0 + i;
      v[i] = (kk < 8) ? (bf16)wih1[n * 8 + kk] : (bf16)0.f;
    }
  } else {
    int r    = fid - F_LIN;
    int ks   = r >> 6;
    int lane = r & 63;
    int n = lane & 31;
    int k = ks * 16 + (lane >> 5) * 8;
#pragma unroll
    for (int i = 0; i < 8; ++i)
      v[i] = (n < NOUT) ? (bf16)lin_w[n * 256 + k + i] : (bf16)0.f;
  }
  g_pk[fid] = v;
}

__global__ void zero_flags_kernel() {
  int tid = threadIdx.x;  // 1024
  for (int i = tid; i < 2 * NG * 64; i += 1024) ((unsigned*)g_flags)[i] = 0u;
}

__device__ __forceinline__ float sigmoidf_(float x) { return 1.f / (1.f + __expf(-x)); }
__device__ __forceinline__ float tanhf_(float x) {
  float e = __expf(-2.f * x);
  return (1.f - e) / (1.f + e);
}
__device__ __forceinline__ f32x16 z16() {
  f32x16 z;
#pragma unroll
  for (int i = 0; i < 16; ++i) z[i] = 0.f;
  return z;
}
__device__ __forceinline__ u16 bfb(float x) { bf16 b = (bf16)x; return *(u16*)&b; }

// pipelined IF-coherent payload load (identical semantics to relaxed agent
// atomic load; straight-line asm so 8 issues share one vmcnt wait)
__device__ __forceinline__ void ld_u64_issue(u64& d, const u64* p) {
  asm volatile("global_load_dwordx2 %0, %1, off sc0 sc1" : "=v"(d) : "v"(p) : "memory");
}

// bounded spin: deadlock valve (~0.1s) turns a protocol bug into a wrong
// answer + counters instead of a 600s harness timeout.
__device__ __forceinline__ void spin_wait(int ph, int grp, int l, unsigned tgt) {
  const unsigned* f = &g_flags[ph][grp][0];
  for (int it = 0; it < (1 << 22); ++it) {
    unsigned v = 0xFFFFFFFFu;
    if (l < GC) v = __hip_atomic_load(&f[l], __ATOMIC_RELAXED, __HIP_MEMORY_SCOPE_AGENT);
    if (__all((int)(v >= tgt))) return;
    __builtin_amdgcn_s_sleep(1);
  }
}

// swizzled bf16 A-tile element (row, unit u of 8 cols): conflict-free ds_read_b128
__device__ __forceinline__ bf16x8 ldA(const u16* buf, int row, int u) {
  return *(const bf16x8*)&buf[(row << 8) + ((u ^ (row & 31)) << 3)];
}
__device__ __forceinline__ bf16x8 ldX(const u16* xsb, int row, int hv) {
  return *(const bf16x8*)&xsb[(row << 4) + (hv << 3)];
}

__device__ __forceinline__ void dump2(float* tile, int hv, int col,
                                      const f32x16& a0, const f32x16& a1) {
#pragma unroll
  for (int q = 0; q < 16; ++q) {
    int mm = (q & 3) + 8 * (q >> 2) + 4 * hv;
    tile[mm * 33 + col]        = a0[q];
    tile[(32 + mm) * 33 + col] = a1[q];
  }
}

#define CHAIN2(BUF, KOFF, KS0, NKS, A0, A1)                      \
  { _Pragma("unroll")                                            \
    for (int kk = 0; kk < (NKS); ++kk) {                         \
      int uu_ = 2 * ((KS0) + kk) + hv;                           \
      A0 = MFMA(ldA(BUF, col, uu_), wf[(KOFF) + kk], A0);        \
      A1 = MFMA(ldA(BUF, 32 + col, uu_), wf[(KOFF) + kk], A1);   \
    } }

// 8-CU groups, weights register-resident. CU g owns h-dims [32g,32g+32).
// Waves 0/1/2 = L1 r/z/n (whh1+wih1, phase A); 3/4/5 = L2 gi r/z/n (wih2,
// phase B); 6/7 = L2 gh (whh2) — run during the h1-exchange spin window.
// Exchange: coalesced u64 slabs ([quad][row]) via IF-coherent ops + relaxed
// agent-atomic flags with parity double-buffer (round-3 proven protocol).
__global__ __launch_bounds__(512, 2) void gru_kernel(
    const int* __restrict__ plen_p,
    const float* __restrict__ rnn_in,
    const float* __restrict__ out0,
    const float* __restrict__ h01,
    const float* __restrict__ h02,
    const float* __restrict__ bih1, const float* __restrict__ bhh1,
    const float* __restrict__ bih2, const float* __restrict__ bhh2,
    const float* __restrict__ lin_b,
    float* __restrict__ out) {
  __shared__ u16 h1bf[64 * 256];      // full h1, bf16 bits, swizzled
  __shared__ u16 h2bf[64 * 256];
  __shared__ float preS[8][64 * 33];  // gate preact tiles (+1 pad)
  __shared__ float Mst1[64 * 33];     // own-slice f32 masters
  __shared__ float Mst2[64 * 33];
  __shared__ u16 xs[64 * 16];         // [out(5), u(3), zeros(8)]

  const int T   = plen_p[0];
  const int tid = threadIdx.x;
  const int wv  = tid >> 6;
  const int l   = tid & 63;
  const int col = l & 31;
  const int hv  = l >> 5;
  const int g   = blockIdx.x >> 5;   // CU rank in group
  const int grp = blockIdx.x & 31;
  const int b0  = grp * BM;

  // ---- register-resident weight fragments ----
  bf16x8 wf[24];
  if (wv < 3) {
    int tile = wv * 8 + g;
#pragma unroll
    for (int k = 0; k < 16; ++k) wf[k] = g_pk[F_WHH1 + (tile * 16 + k) * 64 + l];
    wf[16] = g_pk[F_WIH1 + tile * 64 + l];
  } else if (wv < 6) {
    int tile = (wv - 3) * 8 + g;
#pragma unroll
    for (int k = 0; k < 16; ++k) wf[k] = g_pk[F_WIH2 + (tile * 16 + k) * 64 + l];
  } else {
    int tile = (wv - 6) * 8 + g;
#pragma unroll
    for (int k = 0; k < 16; ++k) wf[k] = g_pk[F_WHH2 + (tile * 16 + k) * 64 + l];
    int tn = 16 + g, kb = (wv - 6) * 8;
#pragma unroll
    for (int k = 0; k < 8; ++k) wf[16 + k] = g_pk[F_WHH2 + (tn * 16 + kb + k) * 64 + l];
  }

  // ---- combine-phase biases (per thread: 4 own jl's) ----
  float br1v[4], bz1v[4], bi1v[4], bh1v[4];
  float br2v[4], bz2v[4], bi2v[4], bh2v[4];
#pragma unroll
  for (int i = 0; i < 4; ++i) {
    int J = 32 * g + 4 * wv + i;
    br1v[i] = bih1[J] + bhh1[J];
    bz1v[i] = bih1[H + J] + bhh1[H + J];
    bi1v[i] = bih1[2 * H + J];
    bh1v[i] = bhh1[2 * H + J];
    br2v[i] = bih2[J] + bhh2[J];
    bz2v[i] = bih2[H + J] + bhh2[H + J];
    bi2v[i] = bih2[2 * H + J];
    bh2v[i] = bhh2[2 * H + J];
  }
  float lb = 0.f;
  if ((wv == 2 || wv == 5) && col < NOUT) lb = lin_b[col];

  // ---- LDS init ----
  for (int r = tid; r < 64 * 32; r += 512) {
    int m = r >> 5, u8 = r & 31;
    const float* p1 = h01 + ((size_t)(b0 + m)) * H + u8 * 8;
    const float* p2 = h02 + ((size_t)(b0 + m)) * H + u8 * 8;
    bf16x8 v1, v2;
#pragma unroll
    for (int i = 0; i < 8; ++i) { v1[i] = (bf16)p1[i]; v2[i] = (bf16)p2[i]; }
    int off = (m << 8) + ((u8 ^ (m & 31)) << 3);
    *(bf16x8*)&h1bf[off] = v1;
    *(bf16x8*)&h2bf[off] = v2;
  }
  for (int r = tid; r < 64 * 32; r += 512) {
    int m = r >> 5, jl = r & 31;
    Mst1[m * 33 + jl] = h01[((size_t)(b0 + m)) * H + 32 * g + jl];
    Mst2[m * 33 + jl] = h02[((size_t)(b0 + m)) * H + 32 * g + jl];
  }
  {
    int m = tid >> 3, c = (tid & 7) + 8;
    xs[m * 16 + c] = 0;
    if (tid < 320) { int mm = tid / 5, cc = tid % 5; xs[mm * 16 + cc] = bfb(out0[(size_t)(b0 + mm) * NOUT + cc]); }
    if (tid < 192) { int mm = tid / 3, cc = tid % 3; xs[mm * 16 + 5 + cc] = bfb(rnn_in[((size_t)(b0 + mm)) * 4 + cc]); }
  }
  __syncthreads();

  for (int t = 0; t < T; ++t) {
    const int par = t & 1;
    float ux = 0.f, uy = 0.f, uz = 0.f;

    // ============ phase A: L1 chains (wv0-2); u prefetch (wv3) ============
    if (wv < 2) {
      f32x16 a0 = z16(), a1 = z16();
      CHAIN2(h1bf, 0, 0, 16, a0, a1);
      a0 = MFMA(ldX(xs, col, hv), wf[16], a0);
      a1 = MFMA(ldX(xs, 32 + col, hv), wf[16], a1);
      dump2(preS[wv], hv, col, a0, a1);                 // hr1 / hz1 (merged raw)
    } else if (wv == 2) {
      f32x16 a0 = z16(), a1 = z16();
      a0 = MFMA(ldX(xs, col, hv), wf[16], a0);
      a1 = MFMA(ldX(xs, 32 + col, hv), wf[16], a1);
      dump2(preS[3], hv, col, a0, a1);                  // i_n1 (raw)
      f32x16 c0 = z16(), c1 = z16();
      CHAIN2(h1bf, 0, 0, 16, c0, c1);
      dump2(preS[2], hv, col, c0, c1);                  // h_n1 (raw)
    } else if (wv == 3) {
      if (t + 1 < T) {
        const float4 uu = *(const float4*)&rnn_in[((size_t)(t + 1) * BSZ + b0 + l) * 4];
        ux = uu.x; uy = uu.y; uz = uu.z;
      }
    }
    __syncthreads();  // bar1

    // ============ combine h1 (all waves) ============
    {
      u16x4 v4;
#pragma unroll
      for (int i = 0; i < 4; ++i) {
        int jl = (wv << 2) + i;
        float pr  = preS[0][l * 33 + jl];
        float pz  = preS[1][l * 33 + jl];
        float hn  = preS[2][l * 33 + jl];
        float xin = preS[3][l * 33 + jl];
        float hp  = Mst1[l * 33 + jl];
        float r = sigmoidf_(pr + br1v[i]);
        float z = sigmoidf_(pz + bz1v[i]);
        float n = tanhf_(xin + bi1v[i] + r * (hn + bh1v[i]));
        float h = (1.f - z) * n + z * hp;
        Mst1[l * 33 + jl] = h;
        v4[i] = bfb(h);
      }
      int J0 = (g << 5) + (wv << 2);
      *(u16x4*)&h1bf[(l << 8) + (((J0 >> 3) ^ (l & 31)) << 3) + (J0 & 7)] = v4;
      __hip_atomic_store(&g_hx[0][par][grp][g][(wv << 6) + l],
                         __builtin_bit_cast(u64, v4),
                         __ATOMIC_RELAXED, __HIP_MEMORY_SCOPE_AGENT);  // coalesced
    }
    asm volatile("s_waitcnt vmcnt(0)" ::: "memory");
    __syncthreads();  // bar2  (all payload stores done at coherence point)
    if (tid == 0)
      __hip_atomic_store(&g_flags[0][grp][g], (unsigned)(t + 1),
                         __ATOMIC_RELAXED, __HIP_MEMORY_SCOPE_AGENT);

    // ============ whh2 chains (wv6-7) — hidden under h1 exchange ============
    if (wv >= 6) {
      f32x16 a0 = z16(), a1 = z16();
      CHAIN2(h2bf, 0, 0, 16, a0, a1);
      dump2(preS[4 + (wv & 1)], hv, col, a0, a1);       // gh_r2 / gh_z2
      f32x16 c0 = z16(), c1 = z16();
      if (wv == 6) { CHAIN2(h2bf, 16, 0, 8, c0, c1); }
      else         { CHAIN2(h2bf, 16, 8, 8, c0, c1); }
      dump2(preS[6 + (wv & 1)], hv, col, c0, c1);       // gh_n2 halves
    }

    // ============ h1 exchange: spin + pipelined coalesced gather ============
    spin_wait(0, grp, l, (unsigned)(t + 1));
    {
      const int m = tid & 63, q = tid >> 6;
      u64 vals[GC];
#pragma unroll
      for (int gi = 0; gi < GC; ++gi)
        ld_u64_issue(vals[gi], &g_hx[0][par][grp][gi][(q << 6) + m]);
      asm volatile("s_waitcnt vmcnt(0)" ::: "memory");
      __builtin_amdgcn_sched_barrier(0);
#pragma unroll
      for (int gi = 0; gi < GC; ++gi) {
        int J0 = (gi << 5) + (q << 2);
        *(u16x4*)&h1bf[(m << 8) + (((J0 >> 3) ^ (m & 31)) << 3) + (J0 & 7)] =
            __builtin_bit_cast(u16x4, vals[gi]);
      }
    }
    __syncthreads();  // bar3

    // ============ phase B: wih2 (gi2) chains from fresh h1 ============
    if (wv >= 3 && wv < 6) {
      f32x16 a0 = z16(), a1 = z16();
      CHAIN2(h1bf, 0, 0, 16, a0, a1);
      dump2(preS[wv == 3 ? 0 : (wv == 4 ? 1 : 3)], hv, col, a0, a1);
    }
    __syncthreads();  // bar4

    // ============ combine h2 (all waves) ============
    {
      u16x4 v4;
#pragma unroll
      for (int i = 0; i < 4; ++i) {
        int jl = (wv << 2) + i;
        float gir = preS[0][l * 33 + jl], ghr = preS[4][l * 33 + jl];
        float giz = preS[1][l * 33 + jl], ghz = preS[5][l * 33 + jl];
        float gin = preS[3][l * 33 + jl];
        float ghn = preS[6][l * 33 + jl] + preS[7][l * 33 + jl];
        float hp  = Mst2[l * 33 + jl];
        float r = sigmoidf_(gir + ghr + br2v[i]);
        float z = sigmoidf_(giz + ghz + bz2v[i]);
        float n = tanhf_(gin + bi2v[i] + r * (ghn + bh2v[i]));
        float h = (1.f - z) * n + z * hp;
        Mst2[l * 33 + jl] = h;
        v4[i] = bfb(h);
      }
      int J0 = (g << 5) + (wv << 2);
      *(u16x4*)&h2bf[(l << 8) + (((J0 >> 3) ^ (l & 31)) << 3) + (J0 & 7)] = v4;
      __hip_atomic_store(&g_hx[1][par][grp][g][(wv << 6) + l],
                         __builtin_bit_cast(u64, v4),
                         __ATOMIC_RELAXED, __HIP_MEMORY_SCOPE_AGENT);
    }
    asm volatile("s_waitcnt vmcnt(0)" ::: "memory");
    __syncthreads();  // bar5
    if (tid == 0)
      __hip_atomic_store(&g_flags[1][grp][g], (unsigned)(t + 1),
                         __ATOMIC_RELAXED, __HIP_MEMORY_SCOPE_AGENT);

    // ============ h2 exchange: spin + pipelined coalesced gather ============
    spin_wait(1, grp, l, (unsigned)(t + 1));
    {
      const int m = tid & 63, q = tid >> 6;
      u64 vals[GC];
#pragma unroll
      for (int gi = 0; gi < GC; ++gi)
        ld_u64_issue(vals[gi], &g_hx[1][par][grp][gi][(q << 6) + m]);
      asm volatile("s_waitcnt vmcnt(0)" ::: "memory");
      __builtin_amdgcn_sched_barrier(0);
#pragma unroll
      for (int gi = 0; gi < GC; ++gi) {
        int J0 = (gi << 5) + (q << 2);
        *(u16x4*)&h2bf[(m << 8) + (((J0 >> 3) ^ (m & 31)) << 3) + (J0 & 7)] =
            __builtin_bit_cast(u16x4, vals[gi]);
      }
    }
    __syncthreads();  // bar6

    // ============ head: out = h2 @ lin^T (redundant per CU) + next x ============
    if (wv == 2 || wv == 5) {
      int mt = (wv == 2) ? 0 : 1;
      f32x16 a0 = z16();
#pragma unroll
      for (int ks = 0; ks < 16; ++ks)
        a0 = MFMA(ldA(h2bf, mt * 32 + col, 2 * ks + hv), g_pk[F_LIN + ks * 64 + l], a0);
      if (col < NOUT) {
#pragma unroll
        for (int q = 0; q < 16; ++q) {
          int m = mt * 32 + (q & 3) + 8 * (q >> 2) + 4 * hv;
          float v = a0[q] + lb;
          if (g == 0) out[((size_t)(b0 + m) * T + t) * NOUT + col] = v;
          xs[(m << 4) + col] = bfb(v);
        }
      }
    } else if (wv == 3) {
      if (t + 1 < T) {
        xs[(l << 4) + 5] = bfb(ux);
        xs[(l << 4) + 6] = bfb(uy);
        xs[(l << 4) + 7] = bfb(uz);
      }
    }
    __syncthreads();  // bar7
  }
}

extern "C" void kernel_launch(void* const* d_in, const int* in_sizes, int n_in,
                              void* d_out, int out_size, void* d_ws, size_t ws_size,
                              hipStream_t stream) {
  (void)in_sizes; (void)n_in; (void)out_size; (void)d_ws; (void)ws_size;
  const int*   plen  = (const int*)d_in[0];
  const float* rnn   = (const float*)d_in[1];
  const float* out0  = (const float*)d_in[2];
  const float* h01   = (const float*)d_in[3];
  const float* h02   = (const float*)d_in[4];
  const float* wih1  = (const float*)d_in[5];
  const float* whh1  = (const float*)d_in[6];
  const float* bih1  = (const float*)d_in[7];
  const float* bhh1  = (const float*)d_in[8];
  const float* wih2  = (const float*)d_in[9];
  const float* whh2  = (const float*)d_in[10];
  const float* bih2  = (const float*)d_in[11];
  const float* bhh2  = (const float*)d_in[12];
  const float* lin_w = (const float*)d_in[13];
  const float* lin_b = (const float*)d_in[14];

  zero_flags_kernel<<<1, 1024, 0, stream>>>();
  prepack_kernel<<<(F_TOTAL + 255) / 256, 256, 0, stream>>>(wih1, whh1, wih2, whh2, lin_w);
  gru_kernel<<<NG * GC, 512, 0, stream>>>(plen, rnn, out0, h01, h02,
                                          bih1, bhh1, bih2, bhh2, lin_b,
                                          (float*)d_out);
}